// Round 1
// baseline (5514.653 us; speedup 1.0000x reference)
//
#include <hip/hip_runtime.h>

#define BATCH   4
#define NPTS    8192
#define NPOINT  2048
#define NSAMPLE 32
#define NCH     67
#define NOUT    128
#define NP      4      // centers per conv block

// ---------------------------------------------------------------------------
// FPS: one block per batch. 1024 threads x 8 points each, all in registers.
// Bit-exact vs reference: per-op rounding (contract off), sum order
// ((dx^2+dy^2)+dz^2), argmax = first occurrence of max (smallest index wins
// ties at every reduction level).
// ---------------------------------------------------------------------------
__global__ __launch_bounds__(1024) void fps_kernel(
    const float* __restrict__ points, float* __restrict__ new_xyz,
    int* __restrict__ inds)
{
#pragma clang fp contract(off)
    const int b = blockIdx.x;
    const int t = threadIdx.x;
    const float* pts = points + (size_t)b * NPTS * 3;

    float x[8], y[8], z[8], dist[8];
#pragma unroll
    for (int k = 0; k < 8; ++k) {
        int i = t + (k << 10);
        x[k] = pts[3 * i + 0];
        y[k] = pts[3 * i + 1];
        z[k] = pts[3 * i + 2];
        dist[k] = 10000000000.0f;
    }

    __shared__ float rv[16];
    __shared__ int   ri[16];
    __shared__ float cbuf[3];
    __shared__ int   sel;

    // first center: index 0 (owned by thread 0, k=0)
    if (t == 0) {
        cbuf[0] = x[0]; cbuf[1] = y[0]; cbuf[2] = z[0];
        inds[b * NPOINT] = 0;
        float* o = new_xyz + (size_t)b * NPOINT * 3;
        o[0] = x[0]; o[1] = y[0]; o[2] = z[0];
    }
    __syncthreads();
    float cx = cbuf[0], cy = cbuf[1], cz = cbuf[2];

    for (int it = 1; it < NPOINT; ++it) {
        float bv = -1.0f;
        int   bi = 0;
#pragma unroll
        for (int k = 0; k < 8; ++k) {
            float dx = x[k] - cx;
            float dy = y[k] - cy;
            float dz = z[k] - cz;
            float d  = ((dx * dx) + (dy * dy)) + (dz * dz);
            float dk = dist[k];
            dk = fminf(dk, d);
            dist[k] = dk;
            // k ascending => index ascending within thread; strict > keeps
            // the earlier (smaller) index on ties.
            if (dk > bv) { bv = dk; bi = t + (k << 10); }
        }
        // wave (64-lane) argmax reduce with index tie-break
#pragma unroll
        for (int off = 32; off >= 1; off >>= 1) {
            float ov = __shfl_down(bv, off);
            int   oi = __shfl_down(bi, off);
            if (ov > bv || (ov == bv && oi < bi)) { bv = ov; bi = oi; }
        }
        const int w = t >> 6;
        if ((t & 63) == 0) { rv[w] = bv; ri[w] = bi; }
        __syncthreads();
        if (t == 0) {
            float fv = rv[0]; int fi = ri[0];
#pragma unroll
            for (int q = 1; q < 16; ++q) {
                float v = rv[q]; int i2 = ri[q];
                if (v > fv || (v == fv && i2 < fi)) { fv = v; fi = i2; }
            }
            sel = fi;
            inds[b * NPOINT + it] = fi;
        }
        __syncthreads();
        const int s = sel;
        if ((s & 1023) == t) {            // owner thread broadcasts center
            const int k = s >> 10;
            cbuf[0] = x[k]; cbuf[1] = y[k]; cbuf[2] = z[k];
            float* o = new_xyz + ((size_t)b * NPOINT + it) * 3;
            o[0] = x[k]; o[1] = y[k]; o[2] = z[k];
        }
        __syncthreads();
        cx = cbuf[0]; cy = cbuf[1]; cz = cbuf[2];
    }
}

// ---------------------------------------------------------------------------
// Ball query: one wave per center. Ascending scan collects the first (i.e.
// smallest-index) NSAMPLE points with d2 < r2, padded with the first hit.
// ---------------------------------------------------------------------------
__global__ __launch_bounds__(256) void ballq_kernel(
    const float* __restrict__ points, const float* __restrict__ new_xyz,
    int* __restrict__ ballidx)
{
#pragma clang fp contract(off)
    const int wid  = (int)((blockIdx.x * 256 + threadIdx.x) >> 6);
    const int lane = threadIdx.x & 63;
    const int b = wid / NPOINT;
    const float* ctr = new_xyz + (size_t)wid * 3;
    const float cx = ctr[0], cy = ctr[1], cz = ctr[2];
    const float* pts = points + (size_t)b * NPTS * 3;
    int* out = ballidx + (size_t)wid * NSAMPLE;
    // NumPy/JAX promote the python double 0.04 to f32 — NOT 0.2f*0.2f.
    const float r2 = (float)(0.2 * 0.2);

    int cnt = 0;
    int first = 0;
    bool havefirst = false;
    for (int base = 0; base < NPTS && cnt < NSAMPLE; base += 64) {
        const int j = base + lane;
        float dx = pts[3 * j + 0] - cx;
        float dy = pts[3 * j + 1] - cy;
        float dz = pts[3 * j + 2] - cz;
        float d2 = ((dx * dx) + (dy * dy)) + (dz * dz);
        const bool in = d2 < r2;
        unsigned long long m = __ballot(in);
        if (in) {
            int pos = cnt + __popcll(m & ((1ull << lane) - 1ull));
            if (pos < NSAMPLE) out[pos] = j;
        }
        if (!havefirst && m != 0ull) {
            first = base + (__ffsll((long long)m) - 1);
            havefirst = true;
        }
        cnt += __popcll(m);
    }
    if (lane >= cnt && lane < NSAMPLE) out[lane] = first;  // pad with first
}

// ---------------------------------------------------------------------------
// Gather + conv: block = NP centers, 128 threads = 128 output channels.
// g[p][c][s] staged in LDS; fp32 FMA accumulate (tolerance is loose here).
// ---------------------------------------------------------------------------
__global__ __launch_bounds__(128) void conv_kernel(
    const float* __restrict__ points, const float* __restrict__ features,
    const float* __restrict__ weight, const float* __restrict__ new_xyz,
    const int* __restrict__ ballidx, float* __restrict__ conv_out)
{
    __shared__ float g[NP][NCH][NSAMPLE];
    const int t = threadIdx.x;
    const int bp0 = blockIdx.x * NP;                // global center index base
    const int b = bp0 / NPOINT;
    const float* pts = points + (size_t)b * NPTS * 3;
    const float* fts = features + (size_t)b * NPTS * 64;

    // gather: 128 slots == 128 threads; slot = p*32+s
    {
        const int p = t >> 5;
        const int s = t & 31;
        const int ci = bp0 + p;
        const int j = ballidx[(size_t)ci * NSAMPLE + s];
        const float* ctr = new_xyz + (size_t)ci * 3;
        const float* pj = pts + 3 * j;
        g[p][0][s] = pj[0] - ctr[0];
        g[p][1][s] = pj[1] - ctr[1];
        g[p][2][s] = pj[2] - ctr[2];
        const float4* fj = (const float4*)(fts + (size_t)j * 64);
#pragma unroll
        for (int c4 = 0; c4 < 16; ++c4) {
            float4 v = fj[c4];
            g[p][3 + 4 * c4 + 0][s] = v.x;
            g[p][3 + 4 * c4 + 1][s] = v.y;
            g[p][3 + 4 * c4 + 2][s] = v.z;
            g[p][3 + 4 * c4 + 3][s] = v.w;
        }
    }
    __syncthreads();

    const int o = t;
    float acc0 = 0.f, acc1 = 0.f, acc2 = 0.f, acc3 = 0.f;
    const float* wr = weight + (size_t)o * NCH * NSAMPLE;
    for (int c = 0; c < NCH; ++c) {
        const float4* w4 = (const float4*)(wr + c * NSAMPLE);
#pragma unroll
        for (int s4 = 0; s4 < 8; ++s4) {
            float4 wv = w4[s4];
            float4 g0 = *(const float4*)&g[0][c][s4 * 4];
            float4 g1 = *(const float4*)&g[1][c][s4 * 4];
            float4 g2 = *(const float4*)&g[2][c][s4 * 4];
            float4 g3 = *(const float4*)&g[3][c][s4 * 4];
            acc0 += g0.x * wv.x + g0.y * wv.y + g0.z * wv.z + g0.w * wv.w;
            acc1 += g1.x * wv.x + g1.y * wv.y + g1.z * wv.z + g1.w * wv.w;
            acc2 += g2.x * wv.x + g2.y * wv.y + g2.z * wv.z + g2.w * wv.w;
            acc3 += g3.x * wv.x + g3.y * wv.y + g3.z * wv.z + g3.w * wv.w;
        }
    }
    float* outp = conv_out + (size_t)bp0 * NOUT;
    outp[0 * NOUT + o] = acc0;
    outp[1 * NOUT + o] = acc1;
    outp[2 * NOUT + o] = acc2;
    outp[3 * NOUT + o] = acc3;
}

extern "C" void kernel_launch(void* const* d_in, const int* in_sizes, int n_in,
                              void* d_out, int out_size, void* d_ws, size_t ws_size,
                              hipStream_t stream)
{
    const float* points   = (const float*)d_in[0];
    const float* features = (const float*)d_in[1];
    const float* weight   = (const float*)d_in[2];

    float* new_xyz = (float*)d_out;                              // (4,2048,3)
    float* conv    = (float*)d_out + (size_t)BATCH * NPOINT * 3; // (4,2048,128)

    int* inds    = (int*)d_ws;                 // (4,2048)
    int* ballidx = inds + BATCH * NPOINT;      // (4,2048,32)

    fps_kernel<<<BATCH, 1024, 0, stream>>>(points, new_xyz, inds);
    ballq_kernel<<<(BATCH * NPOINT * 64) / 256, 256, 0, stream>>>(points, new_xyz, ballidx);
    conv_kernel<<<(BATCH * NPOINT) / NP, 128, 0, stream>>>(points, features, weight, new_xyz, ballidx, conv);
}